// Round 11
// baseline (83.176 us; speedup 1.0000x reference)
//
#include <hip/hip_runtime.h>

// Problem constants (from reference setup_inputs)
constexpr int cB = 32, cC = 6, cT = 64;
constexpr int cK = 8, cN = 128;
constexpr int cS = 32, cP = 64;
constexpr int NCL = cS * cP;          // 2048 centerline points per batch
constexpr int NW  = 16;               // waves per block
constexpr float F_EPS = 1e-6f;
constexpr float F_THRESHOLD = 0.5f;

// One block per (b,c): 1024 threads = 16 waves; lane = t (64 points in lanes).
// Wave w owns a segment chunk (polyline k=w/2, n-half) and a centerline chunk
// (128 pts). All table accesses use wave-uniform indices -> scalar loads
// (s_load) feeding VALU as free SGPR operands: the hot loops have NO vector
// memory and NO shuffles, attacking the ~34% issue-efficiency cap seen in
// R4-R10. Chunk results combine via 8KB LDS; direct store (no atomics).
__global__ __launch_bounds__(1024) void offroad_kernel(
    const float* __restrict__ points,         // (B, C, T, 2)
    const float* __restrict__ road_boundary,  // (B, K, N, 2)
    const float* __restrict__ centerlines,    // (B, S, P, 2)
    float* __restrict__ out)                  // (B, C)
{
    __shared__ float s_f[NW][cT];
    __shared__ int   s_i[NW][cT];

    const int bc   = blockIdx.x;          // 0 .. 191
    const int b    = bc / cC;
    const int tid  = threadIdx.x;
    const int lane = tid & 63;            // = t
    const int wv   = tid >> 6;            // 0 .. 15

    const float2* __restrict__ pts2 =
        (const float2*)(points + (size_t)bc * cT * 2);
    const float2 pt = pts2[lane];         // coalesced per-lane load
    const float px = pt.x, py = pt.y;

    const float2* __restrict__ rb2 =
        (const float2*)(road_boundary + (size_t)b * cK * cN * 2);
    const float4* __restrict__ cl4 =
        (const float4*)(centerlines + (size_t)b * NCL * 2);
    const float2* __restrict__ cl2 = (const float2*)cl4;

    // ---- Pass 1: centerline argmin over this wave's 128-point chunk ----
    float bd = 3.4e38f; int bi = 0x7fffffff;
    const int j0 = wv * (NCL / 2 / NW);   // 64 float4 per wave
    #pragma unroll 4
    for (int jj = 0; jj < NCL / 2 / NW; ++jj) {
        const int jf = j0 + jj;           // wave-uniform -> s_load
        const float4 cp = cl4[jf];
        float dxa = px - cp.x, dya = py - cp.y;
        float d2a = dxa * dxa + dya * dya;
        float dxb = px - cp.z, dyb = py - cp.w;
        float d2b = dxb * dxb + dyb * dyb;
        const int ia = 2 * jf;
        float dmin = d2a; int imin = ia;
        if (d2b < d2a) { dmin = d2b; imin = ia + 1; }  // lower idx on tie
        if (dmin < bd) { bd = dmin; bi = imin; }       // strict < keeps first
    }
    s_f[wv][lane] = bd; s_i[wv][lane] = bi;
    __syncthreads();
    // every lane combines the 16 wave-candidates for its t (idx tie-break)
    bd = s_f[0][lane]; bi = s_i[0][lane];
    #pragma unroll
    for (int w2 = 1; w2 < NW; ++w2) {
        float od = s_f[w2][lane]; int oi = s_i[w2][lane];
        if (od < bd || (od == bd && oi < bi)) { bd = od; bi = oi; }
    }
    const float2 cc = cl2[bi];            // per-lane gather, L2-hot, one-time
    const float dax = cc.x - px, day = cc.y - py;   // da = a2 - a1
    __syncthreads();                      // s_f/s_i reuse protection

    // ---- Pass 2: segment distance + intersection over wave's chunk ----
    // wave w: polyline k = w/2, n-range [n0, n0+64); n==127 is clamped to a
    // repeat of segment 126 (min unaffected) and masked out of the hit test.
    float mind2 = 3.4e38f; int hit = 0;
    const int k  = wv >> 1;
    const int n0 = (wv & 1) ? 64 : 0;
    const float2* __restrict__ rbv = rb2 + k * cN;
    #pragma unroll 4
    for (int jj = 0; jj < 64; ++jj) {
        const int n  = n0 + jj;           // wave-uniform
        const int ok = (n < cN - 1) ? 1 : 0;
        const int nl = ok ? n : (cN - 2);
        const float2 a = rbv[nl];         // s_load
        const float2 e = rbv[nl + 1];     // s_load (merged with above)
        const float dx = e.x - a.x, dy = e.y - a.y;
        const float inv_e2 = __builtin_amdgcn_rcpf(dx * dx + dy * dy + F_EPS);
        // shared: v1 = p - a (== reference's dp = a1 - b1)
        float v1x = px - a.x, v1y = py - a.y;
        // point-to-segment distance
        float proj = (v1x * dx + v1y * dy) * inv_e2;
        proj = __builtin_amdgcn_fmed3f(proj, 0.0f, 1.0f);
        float ex = v1x - dx * proj;
        float ey = v1y - dy * proj;
        mind2 = fminf(mind2, ex * ex + ey * ey);
        // intersection, division-free (w = cross(da,db)+EPS):
        //   t,u in [0,1]  <=>  ct*w in [0,w^2] and cu*w in [0,w^2]
        float w   = dax * dy - day * dx + F_EPS;
        float w2s = w * w;
        float ct  = (dax * v1y - day * v1x) * w;
        float cu  = (dx * v1y - dy * v1x) * w;
        bool inb = (ct >= 0.0f) & (ct <= w2s) & (cu >= 0.0f) & (cu <= w2s);
        hit |= ok & (int)inb;
    }

    s_f[wv][lane] = mind2; s_i[wv][lane] = hit;
    __syncthreads();

    // ---- wave 0: final combine + loss + sum over t, direct store ----
    if (wv == 0) {
        float m = s_f[0][lane]; int h = s_i[0][lane];
        #pragma unroll
        for (int w2 = 1; w2 < NW; ++w2) {
            m = fminf(m, s_f[w2][lane]);
            h |= s_i[w2][lane];
        }
        float md  = sqrtf(m);
        float val = fmaxf((h ? md : -md) + F_THRESHOLD, 0.0f);
        #pragma unroll
        for (int off = 32; off >= 1; off >>= 1)
            val += __shfl_down(val, off);
        if (lane == 0)
            out[bc] = val;
    }
}

extern "C" void kernel_launch(void* const* d_in, const int* in_sizes, int n_in,
                              void* d_out, int out_size, void* d_ws, size_t ws_size,
                              hipStream_t stream) {
    const float* points      = (const float*)d_in[0];
    const float* boundary    = (const float*)d_in[1];
    const float* centerlines = (const float*)d_in[2];
    float* out = (float*)d_out;
    offroad_kernel<<<cB * cC, 1024, 0, stream>>>(points, boundary, centerlines, out);
}